// Round 6
// baseline (8925.568 us; speedup 1.0000x reference)
//
#include <hip/hip_runtime.h>

// liGRU on MI355X.
// Phase 1: P[64000][2048](bf16, in d_out) = x @ [Wh;Wz]^T + column sums/sumsq.
// Phase 2: persistent scan, 8 groups (4 batch rows) x 16 WGs x 8 waves (512 thr).
//          Data plane (proven r2/r5): u64 records { tag=t+1 (hi32) | 2x bf16 (lo32) },
//          system-scope relaxed -- flag IS the data, verified per-record on read.
//          NEW control plane: per-wave 4B tag array. Producer wave: 16 record
//          stores -> vmcnt(0) (acked at L3) -> one tag store. Consumer: ONLY
//          wave 0 polls the 128 tags (512B/iter/WG, ~30x less L3 poll traffic
//          than polling 16KB of records from all 8 waves); waves 1-7 park on a
//          raw s_barrier. After the flip, all waves bulk-read records once and
//          STILL verify their embedded tags (retry loop) -- correctness never
//          depends on the tag-array shortcut.
//          Round-4 lesson kept: no hand-written sc0/sc1 cache-bit asm.
//          WAR on d_out aliasing (P bf16 vs out f32): P[t+2] read issued at step
//          t completes before the step-t vmcnt(0) that precedes the tag(t+1)
//          store; any writer of out[t+2] passed poll(t+2) => saw all tags>=t+1
//          => all P[t+2] reads done. Prologue rendezvous covers P[0..1].

#define T_STEPS 2000
#define NCOLS   2048
#define PKEEP   0.8f
#define BN_EPSF 1e-5f
#define NWG     128

typedef __attribute__((ext_vector_type(8))) short bf16x8;
typedef __attribute__((ext_vector_type(4))) float f32x4;
typedef __attribute__((ext_vector_type(4))) unsigned int u32x4;

static __device__ __forceinline__ unsigned short f2bf(float f) {
  unsigned u = __builtin_bit_cast(unsigned, f);
  unsigned r = u + 0x7FFFu + ((u >> 16) & 1u);   // RNE
  return (unsigned short)(r >> 16);
}
static __device__ __forceinline__ float bf2f(unsigned short s) {
  unsigned u = ((unsigned)s) << 16;
  return __builtin_bit_cast(float, u);
}

// ---------------- K1: convert [Wh;Wz] f32 -> bf16 ----------------
__global__ void k_convw(const float* __restrict__ Wh, const float* __restrict__ Wz,
                        unsigned short* __restrict__ Wb) {
  int i = blockIdx.x * 256 + threadIdx.x;
  int e = i * 4;
  int n = e >> 9;
  int k = e & 511;
  const float* src = (n < 1024) ? (Wh + (size_t)n * 512 + k)
                                : (Wz + (size_t)(n - 1024) * 512 + k);
  float4 v = *(const float4*)src;
  *(ushort4*)(Wb + e) = make_ushort4(f2bf(v.x), f2bf(v.y), f2bf(v.z), f2bf(v.w));
}

// ---------------- K2: GEMM  P = x @ Wb^T  (+ BN stats) ----------------
__global__ __launch_bounds__(256, 2) void k_gemm(
    const float* __restrict__ X, const unsigned short* __restrict__ Wb,
    unsigned short* __restrict__ P, float* __restrict__ sums, float* __restrict__ sumsq) {
  __shared__ __align__(16) unsigned short As[128 * 32];
  __shared__ __align__(16) unsigned short Bs[128 * 32];
  const int tid  = threadIdx.x;
  const int bm   = blockIdx.x >> 4, bn = blockIdx.x & 15;
  const int lane = tid & 63, wid = tid >> 6;
  const int wm   = wid >> 1, wn = wid & 1;
  const int lrow = lane & 15, lk = lane >> 4;

  f32x4 acc[4][4] = {};

  for (int kk = 0; kk < 512; kk += 32) {
    __syncthreads();
#pragma unroll
    for (int j = 0; j < 2; ++j) {
      int c = j * 256 + wid * 64 + lane;
      int brow = c >> 2, b8 = (c & 3) * 8;
      const unsigned short* gp = Wb + (size_t)(bn * 128 + brow) * 512 + kk + b8;
      __builtin_amdgcn_global_load_lds(
          (const __attribute__((address_space(1))) unsigned int*)gp,
          (__attribute__((address_space(3))) unsigned int*)(Bs + (size_t)(j * 256 + wid * 64) * 8),
          16, 0, 0);
    }
    {
      int arow = tid >> 1, ahalf = tid & 1;
      const float4* xp = (const float4*)(X + (size_t)(bm * 128 + arow) * 512 + kk + ahalf * 16);
      unsigned v[8];
#pragma unroll
      for (int j = 0; j < 4; ++j) {
        float4 f = xp[j];
        v[j * 2 + 0] = (unsigned)f2bf(f.x) | ((unsigned)f2bf(f.y) << 16);
        v[j * 2 + 1] = (unsigned)f2bf(f.z) | ((unsigned)f2bf(f.w) << 16);
      }
      u32x4* ap = (u32x4*)(As + arow * 32 + ahalf * 16);
      u32x4 t0 = {v[0], v[1], v[2], v[3]};
      u32x4 t1 = {v[4], v[5], v[6], v[7]};
      ap[0] = t0; ap[1] = t1;
    }
    __syncthreads();

    bf16x8 af[4], bfr[4];
#pragma unroll
    for (int mt = 0; mt < 4; ++mt)
      af[mt] = *(const bf16x8*)(As + (wm * 64 + mt * 16 + lrow) * 32 + lk * 8);
#pragma unroll
    for (int nt = 0; nt < 4; ++nt)
      bfr[nt] = *(const bf16x8*)(Bs + (wn * 64 + nt * 16 + lrow) * 32 + lk * 8);
#pragma unroll
    for (int mt = 0; mt < 4; ++mt)
#pragma unroll
      for (int nt = 0; nt < 4; ++nt)
        acc[mt][nt] = __builtin_amdgcn_mfma_f32_16x16x32_bf16(af[mt], bfr[nt], acc[mt][nt], 0, 0, 0);
  }

#pragma unroll
  for (int mt = 0; mt < 4; ++mt)
#pragma unroll
    for (int nt = 0; nt < 4; ++nt) {
      f32x4 a = acc[mt][nt];
      int gcol  = bn * 128 + wn * 64 + nt * 16 + lrow;
      int grow0 = bm * 128 + wm * 64 + mt * 16 + lk * 4;
#pragma unroll
      for (int rr = 0; rr < 4; ++rr)
        P[(size_t)(grow0 + rr) * NCOLS + gcol] = f2bf(a[rr]);
    }
#pragma unroll
  for (int nt = 0; nt < 4; ++nt) {
    float s = 0.f, q = 0.f;
#pragma unroll
    for (int mt = 0; mt < 4; ++mt) {
      f32x4 a = acc[mt][nt];
#pragma unroll
      for (int rr = 0; rr < 4; ++rr) { s += a[rr]; q += a[rr] * a[rr]; }
    }
    s += __shfl_xor(s, 16); s += __shfl_xor(s, 32);
    q += __shfl_xor(q, 16); q += __shfl_xor(q, 32);
    if (lane < 16) {
      int gcol = bn * 128 + wn * 64 + nt * 16 + lrow;
      atomicAdd(&sums[gcol], s);
      atomicAdd(&sumsq[gcol], q);
    }
  }
}

// ---------------- K3: persistent scan ----------------
__global__ __launch_bounds__(512, 2) void k_scan(
    const float* __restrict__ Uh, const float* __restrict__ Uz,
    const float* __restrict__ gwh, const float* __restrict__ bwh,
    const float* __restrict__ gwz, const float* __restrict__ bwz,
    const unsigned short* P,            // aliases d_out (bf16 view) -- no restrict!
    const float* __restrict__ sums, const float* __restrict__ sumsq,
    unsigned long long* hrec,           // [8][2][2048] u64 tagged records
    unsigned int* tags,                 // [8][2][128] u32 per-wave tags
    unsigned int* ctrl,                 // [0] = rendezvous counter
    float* out)                         // aliases d_out (f32 view) -- no restrict!
{
  // hlds double-buffered by parity: [2][4 rows][1024 units] bf16, XOR-swizzled.
  // (Double-buffer needed: a wave's in-flight ds_reads of step t must not race
  //  another wave's step-t+1 ds_writes issued after barrier #1.)
  __shared__ __align__(16) unsigned char hlds[16384];

  const int tid  = threadIdx.x;
  const int lane = tid & 63;
  const int wid  = tid >> 6;            // [0,8)
  const int lrow = lane & 15, lk = lane >> 4;

  const int g    = blockIdx.x & 7;      // group = 4 batch rows
  const int role = blockIdx.x >> 3;     // [0,16): 64-unit block
  const int b0   = g * 4;
  const int u0w  = role * 64 + wid * 8; // this wave's 8 units
  const bool isH = (lrow >= 8);         // B col 0-7 = z, 8-15 = h (packed gates)
  const int unit = u0w + (lrow & 7);
  const int col  = isH ? unit : (1024 + unit);

  // ---- BatchNorm scale/bias for this lane's column ----
  float scl, bia;
  {
    float s = sums[col], q = sumsq[col];
    float gam = isH ? gwh[unit] : gwz[unit];
    float bet = isH ? bwh[unit] : bwz[unit];
    float mean = s * (1.0f / 64000.0f);
    float var  = q * (1.0f / 64000.0f) - mean * mean;
    float rstd = rsqrtf(var + BN_EPSF);
    scl = gam * rstd;
    bia = bet - mean * scl;
  }

  // ---- preload this lane's U row (x PKEEP) as 32 MFMA B-fragments (128 VGPRs)
  const float* urow = (isH ? Uh : Uz) + (size_t)unit * 1024;
  bf16x8 bfrag[32];
#pragma unroll
  for (int kt = 0; kt < 32; ++kt) {
    const float4* p4 = (const float4*)(urow + kt * 32 + lk * 8);
    float4 fa = p4[0], fb = p4[1];
    bf16x8 tv;
    tv[0] = (short)f2bf(fa.x * PKEEP); tv[1] = (short)f2bf(fa.y * PKEEP);
    tv[2] = (short)f2bf(fa.z * PKEEP); tv[3] = (short)f2bf(fa.w * PKEEP);
    tv[4] = (short)f2bf(fb.x * PKEEP); tv[5] = (short)f2bf(fb.y * PKEEP);
    tv[6] = (short)f2bf(fb.z * PKEEP); tv[7] = (short)f2bf(fb.w * PKEEP);
    bfrag[kt] = tv;
  }

  // ---- P prefetch prologue: pf=P[0], pn1=P[1] ----
  unsigned short pf[4], pn1[4];
#pragma unroll
  for (int rr = 0; rr < 4; ++rr) {
    pf[rr]  = P[(size_t)(b0 + rr) * NCOLS + col];
    pn1[rr] = P[(size_t)(32 + b0 + rr) * NCOLS + col];
  }
  __syncthreads();   // full drain: my initial P loads complete

  // ---- rendezvous: ALL WGs' initial P loads drained before anyone can write
  //      out rows 0/1 (WAR on the d_out aliasing).
  if (tid == 0) {
    __hip_atomic_fetch_add(&ctrl[0], 1u, __ATOMIC_RELEASE, __HIP_MEMORY_SCOPE_SYSTEM);
    while (__hip_atomic_load(&ctrl[0], __ATOMIC_RELAXED, __HIP_MEMORY_SCOPE_SYSTEM) < NWG)
      __builtin_amdgcn_s_sleep(8);
  }
  __syncthreads();

  f32x4 hown = {0.f, 0.f, 0.f, 0.f};

  for (int t = 0; t < T_STEPS; ++t) {
    const int par = t & 1;

    // ---- 0. prefetch P[t+2]: issued first, rides until end-of-step vmcnt(0)
    unsigned short pn2[4] = {0, 0, 0, 0};
    if (t + 2 < T_STEPS) {
#pragma unroll
      for (int rr = 0; rr < 4; ++rr)
        pn2[rr] = P[(size_t)((t + 2) * 32 + b0 + rr) * NCOLS + col];
    }

    // ---- 1. discovery: wave 0 polls the 128 per-wave tags; others park ----
    if (wid == 0) {
      const unsigned* tg = tags + (((size_t)(g * 2 + par)) << 7);
      unsigned ta = __hip_atomic_load(tg + lane, __ATOMIC_RELAXED, __HIP_MEMORY_SCOPE_SYSTEM);
      unsigned tb = __hip_atomic_load(tg + 64 + lane, __ATOMIC_RELAXED, __HIP_MEMORY_SCOPE_SYSTEM);
      while (!__all((ta >= (unsigned)t) && (tb >= (unsigned)t))) {
        __builtin_amdgcn_s_sleep(1);
        if (ta < (unsigned)t)
          ta = __hip_atomic_load(tg + lane, __ATOMIC_RELAXED, __HIP_MEMORY_SCOPE_SYSTEM);
        if (tb < (unsigned)t)
          tb = __hip_atomic_load(tg + 64 + lane, __ATOMIC_RELAXED, __HIP_MEMORY_SCOPE_SYSTEM);
      }
    }
    // barrier #1 (raw): tags flipped -> records are readable
    asm volatile("" ::: "memory");
    __builtin_amdgcn_s_barrier();
    asm volatile("" ::: "memory");

    // ---- 2. bulk-read this thread's 4 tagged records; verify tags (safety) ----
    const unsigned long long* rb = hrec + (((size_t)(g * 2 + par)) << 11) + tid;
    unsigned long long rec[4];
#pragma unroll
    for (int j = 0; j < 4; ++j)
      rec[j] = __hip_atomic_load(rb + 512 * j, __ATOMIC_RELAXED, __HIP_MEMORY_SCOPE_SYSTEM);
    while (true) {
      unsigned bad = 0;
#pragma unroll
      for (int j = 0; j < 4; ++j)
        if ((unsigned)(rec[j] >> 32) < (unsigned)t) bad |= (1u << j);
      if (!bad) break;
      __builtin_amdgcn_s_sleep(1);
#pragma unroll
      for (int j = 0; j < 4; ++j)
        if (bad & (1u << j))
          rec[j] = __hip_atomic_load(rb + 512 * j, __ATOMIC_RELAXED, __HIP_MEMORY_SCOPE_SYSTEM);
    }

    // ---- 3. unpack h records into hlds[par] (XOR-swizzled) ----
    unsigned char* hb = hlds + par * 8192;
#pragma unroll
    for (int j = 0; j < 4; ++j) {
      int idx = tid + 512 * j;
      int row = idx >> 9, up = idx & 511;
      int byteoff = (row * 2048 + up * 4) ^ ((row & 3) << 5);
      *(unsigned*)(hb + byteoff) = (unsigned)rec[j];
    }
    // barrier #2 (raw, LDS-only drain): P[t+2] stays in flight
    asm volatile("s_waitcnt lgkmcnt(0)" ::: "memory");
    __builtin_amdgcn_sched_barrier(0);
    __builtin_amdgcn_s_barrier();
    __builtin_amdgcn_sched_barrier(0);

    // ---- 4. packed dot: one MFMA stream computes BOTH gates ----
    f32x4 ac0 = {0.f, 0.f, 0.f, 0.f}, ac1 = ac0, ac2 = ac0, ac3 = ac0;
#pragma unroll
    for (int kt = 0; kt < 32; ++kt) {
      int ab = ((lane & 3) * 2048 + kt * 64 + lk * 16) ^ ((lane & 3) << 5);
      bf16x8 af = *(const bf16x8*)(hb + ab);
      if ((kt & 3) == 0)      ac0 = __builtin_amdgcn_mfma_f32_16x16x32_bf16(af, bfrag[kt], ac0, 0, 0, 0);
      else if ((kt & 3) == 1) ac1 = __builtin_amdgcn_mfma_f32_16x16x32_bf16(af, bfrag[kt], ac1, 0, 0, 0);
      else if ((kt & 3) == 2) ac2 = __builtin_amdgcn_mfma_f32_16x16x32_bf16(af, bfrag[kt], ac2, 0, 0, 0);
      else                    ac3 = __builtin_amdgcn_mfma_f32_16x16x32_bf16(af, bfrag[kt], ac3, 0, 0, 0);
    }
    f32x4 dsum = (ac0 + ac1) + (ac2 + ac3);

    // ---- 5. epilogue: z meets h via shfl_xor(8); lanes 8-15 own the update ----
    float pre[4], oth[4];
#pragma unroll
    for (int rr = 0; rr < 4; ++rr) {
      pre[rr] = dsum[rr] + bf2f(pf[rr]) * scl + bia;
      oth[rr] = __shfl_xor(pre[rr], 8);     // all lanes participate
    }

    if (lk == 0 && isH) {                    // lanes 8..15: pre=h-pre, oth=z-pre
      float hn[4];
#pragma unroll
      for (int rr = 0; rr < 4; ++rr) {
        float zz = 1.0f / (1.0f + __expf(-oth[rr]));
        float hc = fmaxf(pre[rr], 0.0f) * PKEEP;      // relu * 'orig' dropout
        hn[rr] = zz * hown[rr] + (1.0f - zz) * hc;
        hown[rr] = hn[rr];
      }
      float pp[4];
#pragma unroll
      for (int rr = 0; rr < 4; ++rr) pp[rr] = __shfl_xor(hn[rr], 1);  // 8<->9 etc
      if ((lane & 1) == 0) {                 // lanes 8,10,12,14: even units
        unsigned long long* hbn = hrec + (((size_t)(g * 2 + ((t + 1) & 1))) << 11)
                                + (unit >> 1);
        unsigned tagw = (unsigned)(t + 1);
#pragma unroll
        for (int rr = 0; rr < 4; ++rr) {
          unsigned long long rcd = ((unsigned long long)tagw << 32)
                                 | (unsigned)f2bf(hn[rr]) | ((unsigned)f2bf(pp[rr]) << 16);
          __hip_atomic_store(hbn + rr * 512, rcd,
                             __ATOMIC_RELAXED, __HIP_MEMORY_SCOPE_SYSTEM);
        }
#pragma unroll
        for (int rr = 0; rr < 4; ++rr) {
          float2 ov = {hn[rr], pp[rr]};
          *(float2*)(out + (size_t)(t * 32 + b0 + rr) * 1024 + unit) = ov;
        }
      }
    }

    // ---- 6. wave-level ack: records (and P[t+2], out) acked at coherence
    //      point, THEN publish this wave's tag. ----
    asm volatile("s_waitcnt vmcnt(0)" ::: "memory");
    __builtin_amdgcn_sched_barrier(0);
    if (lane == 8) {
      __hip_atomic_store(tags + (((size_t)(g * 2 + ((t + 1) & 1))) << 7) + (role * 8 + wid),
                         (unsigned)(t + 1), __ATOMIC_RELAXED, __HIP_MEMORY_SCOPE_SYSTEM);
    }

#pragma unroll
    for (int rr = 0; rr < 4; ++rr) { pf[rr] = pn1[rr]; pn1[rr] = pn2[rr]; }
  }
}

// ---------------- launch ----------------
extern "C" void kernel_launch(void* const* d_in, const int* in_sizes, int n_in,
                              void* d_out, int out_size, void* d_ws, size_t ws_size,
                              hipStream_t stream) {
  (void)in_sizes; (void)n_in; (void)out_size; (void)ws_size;
  const float* x   = (const float*)d_in[0];
  const float* Wh  = (const float*)d_in[1];
  const float* Wz  = (const float*)d_in[2];
  const float* Uh  = (const float*)d_in[3];
  const float* Uz  = (const float*)d_in[4];
  const float* gwh = (const float*)d_in[5];
  const float* bwh = (const float*)d_in[6];
  const float* gwz = (const float*)d_in[7];
  const float* bwz = (const float*)d_in[8];

  char* ws = (char*)d_ws;
  float*              sums  = (float*)(ws + 0);                  // 8192 B
  float*              sumsq = (float*)(ws + 8192);               // 8192 B
  unsigned long long* hrec  = (unsigned long long*)(ws + 16384); // 262144 B
  unsigned int*       tags  = (unsigned int*)(ws + 278528);      // 8192 B
  unsigned int*       ctrl  = (unsigned int*)(ws + 286720);      // 128 B
  unsigned short*     Wb    = (unsigned short*)(ws + 286848);    // 2 MiB

  // zero stats + records + tags + ctrl every call (graph-replay safe;
  // tag=0 == valid h0=0 records)
  hipMemsetAsync(d_ws, 0, 286848, stream);
  k_convw<<<1024, 256, 0, stream>>>(Wh, Wz, Wb);
  // P (bf16) lives in d_out; scan overwrites it with f32 output in provably-ordered fashion
  k_gemm<<<8000, 256, 0, stream>>>(x, Wb, (unsigned short*)d_out, sums, sumsq);
  k_scan<<<NWG, 512, 0, stream>>>(Uh, Uz, gwh, bwh, gwz, bwz,
                                  (const unsigned short*)d_out, sums, sumsq,
                                  hrec, tags, ctrl, (float*)d_out);
}

// Round 7
// 8030.607 us; speedup vs baseline: 1.1114x; 1.1114x over previous
//
#include <hip/hip_runtime.h>

// liGRU on MI355X.
// Phase 1: P[64000][2048](bf16, in d_out) = x @ [Wh;Wz]^T + column sums/sumsq.
// Phase 2: persistent scan. 8 batch-groups (4 rows each); 128 WGs = 32 unit-roles
//          x 4 pairs; each WG serves TWO groups {2p,2p+1} with the SAME U
//          fragments (U is group-agnostic) -> two independent dependence chains
//          per WG, so each group's exchange latency hides under the other
//          group's compute segment. Per wave: 8 units, packed gates in MFMA B
//          (cols 0-7 = Uz, 8-15 = Uh), z meets h via shfl_xor(8).
//          Exchange protocol = round-2/5 proven: system-scope relaxed u64
//          records { tag=t+1 (hi32) | 2x bf16 h (lo32) } -- flag IS the data,
//          per-record tag verified on read with retry. Group B's records are
//          speculatively loaded early (after A's barrier) and verified later;
//          correctness never depends on the speculation. No sc0/sc1 hand asm
//          (r4 hang lesson), no tag indirection (r6 regression lesson).
//          4 waves x (<=512) VGPR = 1 wave/SIMD: no spill possible.
//          WAR on d_out aliasing (P bf16 read vs out f32 write): P[t+1]
//          prefetches (issued step t-1) are drained by step t's vmcnt(0) BEFORE
//          any tag(t+1) record store; a writer of out[t+1] passed poll(t+1),
//          i.e. saw all tags>=t+1, hence all P[t+1] reads completed. Prologue
//          rendezvous covers P[0..1].

#define T_STEPS 2000
#define NCOLS   2048
#define PKEEP   0.8f
#define BN_EPSF 1e-5f
#define NWG     128

typedef __attribute__((ext_vector_type(8))) short bf16x8;
typedef __attribute__((ext_vector_type(4))) float f32x4;
typedef __attribute__((ext_vector_type(4))) unsigned int u32x4;

static __device__ __forceinline__ unsigned short f2bf(float f) {
  unsigned u = __builtin_bit_cast(unsigned, f);
  unsigned r = u + 0x7FFFu + ((u >> 16) & 1u);   // RNE
  return (unsigned short)(r >> 16);
}
static __device__ __forceinline__ float bf2f(unsigned short s) {
  unsigned u = ((unsigned)s) << 16;
  return __builtin_bit_cast(float, u);
}

// ---------------- K1: convert [Wh;Wz] f32 -> bf16 ----------------
__global__ void k_convw(const float* __restrict__ Wh, const float* __restrict__ Wz,
                        unsigned short* __restrict__ Wb) {
  int i = blockIdx.x * 256 + threadIdx.x;
  int e = i * 4;
  int n = e >> 9;
  int k = e & 511;
  const float* src = (n < 1024) ? (Wh + (size_t)n * 512 + k)
                                : (Wz + (size_t)(n - 1024) * 512 + k);
  float4 v = *(const float4*)src;
  *(ushort4*)(Wb + e) = make_ushort4(f2bf(v.x), f2bf(v.y), f2bf(v.z), f2bf(v.w));
}

// ---------------- K2: GEMM  P = x @ Wb^T  (+ BN stats) ----------------
__global__ __launch_bounds__(256, 2) void k_gemm(
    const float* __restrict__ X, const unsigned short* __restrict__ Wb,
    unsigned short* __restrict__ P, float* __restrict__ sums, float* __restrict__ sumsq) {
  __shared__ __align__(16) unsigned short As[128 * 32];
  __shared__ __align__(16) unsigned short Bs[128 * 32];
  const int tid  = threadIdx.x;
  const int bm   = blockIdx.x >> 4, bn = blockIdx.x & 15;
  const int lane = tid & 63, wid = tid >> 6;
  const int wm   = wid >> 1, wn = wid & 1;
  const int lrow = lane & 15, lk = lane >> 4;

  f32x4 acc[4][4] = {};

  for (int kk = 0; kk < 512; kk += 32) {
    __syncthreads();
#pragma unroll
    for (int j = 0; j < 2; ++j) {
      int c = j * 256 + wid * 64 + lane;
      int brow = c >> 2, b8 = (c & 3) * 8;
      const unsigned short* gp = Wb + (size_t)(bn * 128 + brow) * 512 + kk + b8;
      __builtin_amdgcn_global_load_lds(
          (const __attribute__((address_space(1))) unsigned int*)gp,
          (__attribute__((address_space(3))) unsigned int*)(Bs + (size_t)(j * 256 + wid * 64) * 8),
          16, 0, 0);
    }
    {
      int arow = tid >> 1, ahalf = tid & 1;
      const float4* xp = (const float4*)(X + (size_t)(bm * 128 + arow) * 512 + kk + ahalf * 16);
      unsigned v[8];
#pragma unroll
      for (int j = 0; j < 4; ++j) {
        float4 f = xp[j];
        v[j * 2 + 0] = (unsigned)f2bf(f.x) | ((unsigned)f2bf(f.y) << 16);
        v[j * 2 + 1] = (unsigned)f2bf(f.z) | ((unsigned)f2bf(f.w) << 16);
      }
      u32x4* ap = (u32x4*)(As + arow * 32 + ahalf * 16);
      u32x4 t0 = {v[0], v[1], v[2], v[3]};
      u32x4 t1 = {v[4], v[5], v[6], v[7]};
      ap[0] = t0; ap[1] = t1;
    }
    __syncthreads();

    bf16x8 af[4], bfr[4];
#pragma unroll
    for (int mt = 0; mt < 4; ++mt)
      af[mt] = *(const bf16x8*)(As + (wm * 64 + mt * 16 + lrow) * 32 + lk * 8);
#pragma unroll
    for (int nt = 0; nt < 4; ++nt)
      bfr[nt] = *(const bf16x8*)(Bs + (wn * 64 + nt * 16 + lrow) * 32 + lk * 8);
#pragma unroll
    for (int mt = 0; mt < 4; ++mt)
#pragma unroll
      for (int nt = 0; nt < 4; ++nt)
        acc[mt][nt] = __builtin_amdgcn_mfma_f32_16x16x32_bf16(af[mt], bfr[nt], acc[mt][nt], 0, 0, 0);
  }

#pragma unroll
  for (int mt = 0; mt < 4; ++mt)
#pragma unroll
    for (int nt = 0; nt < 4; ++nt) {
      f32x4 a = acc[mt][nt];
      int gcol  = bn * 128 + wn * 64 + nt * 16 + lrow;
      int grow0 = bm * 128 + wm * 64 + mt * 16 + lk * 4;
#pragma unroll
      for (int rr = 0; rr < 4; ++rr)
        P[(size_t)(grow0 + rr) * NCOLS + gcol] = f2bf(a[rr]);
    }
#pragma unroll
  for (int nt = 0; nt < 4; ++nt) {
    float s = 0.f, q = 0.f;
#pragma unroll
    for (int mt = 0; mt < 4; ++mt) {
      f32x4 a = acc[mt][nt];
#pragma unroll
      for (int rr = 0; rr < 4; ++rr) { s += a[rr]; q += a[rr] * a[rr]; }
    }
    s += __shfl_xor(s, 16); s += __shfl_xor(s, 32);
    q += __shfl_xor(q, 16); q += __shfl_xor(q, 32);
    if (lane < 16) {
      int gcol = bn * 128 + wn * 64 + nt * 16 + lrow;
      atomicAdd(&sums[gcol], s);
      atomicAdd(&sumsq[gcol], q);
    }
  }
}

// ---------------- K3: persistent scan (2 groups per WG) ----------------
__global__ __launch_bounds__(256, 1) void k_scan(
    const float* __restrict__ Uh, const float* __restrict__ Uz,
    const float* __restrict__ gwh, const float* __restrict__ bwh,
    const float* __restrict__ gwz, const float* __restrict__ bwz,
    const unsigned short* P,            // aliases d_out (bf16 view) -- no restrict!
    const float* __restrict__ sums, const float* __restrict__ sumsq,
    unsigned long long* hrec,           // [8][2][2048] u64 tagged records
    unsigned int* ctrl,                 // [0] = rendezvous counter
    float* out)                         // aliases d_out (f32 view) -- no restrict!
{
  // [group(A/B)][parity][4 rows][1024 units] bf16, XOR-swizzled
  __shared__ __align__(16) unsigned char hlds[4][8192];

  const int tid  = threadIdx.x;
  const int lane = tid & 63;
  const int wid  = tid >> 6;            // [0,4)
  const int lrow = lane & 15, lk = lane >> 4;

  const int pair = blockIdx.x & 3;      // [0,4): which pair of groups
  const int role = blockIdx.x >> 2;     // [0,32): 32-unit block
  const int gA   = pair * 2, gB = pair * 2 + 1;
  const int b0A  = gA * 4,   b0B = gB * 4;
  const int u0w  = role * 32 + wid * 8; // this wave's 8 units
  const bool isH = (lrow >= 8);         // B col 0-7 = z, 8-15 = h (packed gates)
  const int unit = u0w + (lrow & 7);
  const int col  = isH ? unit : (1024 + unit);  // group-independent

  // ---- BatchNorm scale/bias for this lane's column (shared by both groups) ----
  float scl, bia;
  {
    float s = sums[col], q = sumsq[col];
    float gam = isH ? gwh[unit] : gwz[unit];
    float bet = isH ? bwh[unit] : bwz[unit];
    float mean = s * (1.0f / 64000.0f);
    float var  = q * (1.0f / 64000.0f) - mean * mean;
    float rstd = rsqrtf(var + BN_EPSF);
    scl = gam * rstd;
    bia = bet - mean * scl;
  }

  // ---- preload this lane's U row (x PKEEP) as 32 MFMA B-fragments (128 VGPRs)
  const float* urow = (isH ? Uh : Uz) + (size_t)unit * 1024;
  bf16x8 bfrag[32];
#pragma unroll
  for (int kt = 0; kt < 32; ++kt) {
    const float4* p4 = (const float4*)(urow + kt * 32 + lk * 8);
    float4 fa = p4[0], fb = p4[1];
    bf16x8 tv;
    tv[0] = (short)f2bf(fa.x * PKEEP); tv[1] = (short)f2bf(fa.y * PKEEP);
    tv[2] = (short)f2bf(fa.z * PKEEP); tv[3] = (short)f2bf(fa.w * PKEEP);
    tv[4] = (short)f2bf(fb.x * PKEEP); tv[5] = (short)f2bf(fb.y * PKEEP);
    tv[6] = (short)f2bf(fb.z * PKEEP); tv[7] = (short)f2bf(fb.w * PKEEP);
    bfrag[kt] = tv;
  }

  // ---- P prefetch prologue for both groups: pf=P[0], pn1=P[1] ----
  unsigned short pfA[4], pn1A[4], pfB[4], pn1B[4];
#pragma unroll
  for (int rr = 0; rr < 4; ++rr) {
    pfA[rr]  = P[(size_t)(b0A + rr) * NCOLS + col];
    pn1A[rr] = P[(size_t)(32 + b0A + rr) * NCOLS + col];
    pfB[rr]  = P[(size_t)(b0B + rr) * NCOLS + col];
    pn1B[rr] = P[(size_t)(32 + b0B + rr) * NCOLS + col];
  }
  __syncthreads();   // full drain: my initial P loads complete

  // ---- rendezvous: ALL WGs' initial P loads drained before anyone can write
  //      out rows 0/1 (WAR on the d_out aliasing).
  if (tid == 0) {
    __hip_atomic_fetch_add(&ctrl[0], 1u, __ATOMIC_RELEASE, __HIP_MEMORY_SCOPE_SYSTEM);
    while (__hip_atomic_load(&ctrl[0], __ATOMIC_RELAXED, __HIP_MEMORY_SCOPE_SYSTEM) < NWG)
      __builtin_amdgcn_s_sleep(8);
  }
  __syncthreads();

  float hownA[4] = {0.f, 0.f, 0.f, 0.f};
  float hownB[4] = {0.f, 0.f, 0.f, 0.f};

  for (int t = 0; t < T_STEPS; ++t) {
    const int par  = t & 1;
    const int npar = (t + 1) & 1;
    const unsigned tagw = (unsigned)(t + 1);

    // ================= segment A: blocking poll =================
    const unsigned long long* rbA = hrec + (((size_t)(gA * 2 + par)) << 11) + tid;
    unsigned long long recA[8];
#pragma unroll
    for (int j = 0; j < 8; ++j)
      recA[j] = __hip_atomic_load(rbA + 256 * j, __ATOMIC_RELAXED, __HIP_MEMORY_SCOPE_SYSTEM);
    while (true) {
      unsigned bad = 0;
#pragma unroll
      for (int j = 0; j < 8; ++j)
        if ((unsigned)(recA[j] >> 32) < (unsigned)t) bad |= (1u << j);
      if (!bad) break;
      __builtin_amdgcn_s_sleep(1);
#pragma unroll
      for (int j = 0; j < 8; ++j)
        if (bad & (1u << j))
          recA[j] = __hip_atomic_load(rbA + 256 * j, __ATOMIC_RELAXED, __HIP_MEMORY_SCOPE_SYSTEM);
    }
    // full vmem drain: P[t+1] (issued last step) completed -> WAR proof for tag t+1
    asm volatile("s_waitcnt vmcnt(0)" ::: "memory");

    // prefetch P[t+2] for both groups (rides across everything until next drain)
    unsigned short pn2A[4] = {0, 0, 0, 0}, pn2B[4] = {0, 0, 0, 0};
    if (t + 2 < T_STEPS) {
#pragma unroll
      for (int rr = 0; rr < 4; ++rr) {
        pn2A[rr] = P[(size_t)((t + 2) * 32 + b0A + rr) * NCOLS + col];
        pn2B[rr] = P[(size_t)((t + 2) * 32 + b0B + rr) * NCOLS + col];
      }
    }

    // unpack A -> hlds[0+par]
    {
      unsigned char* hb = hlds[par];
#pragma unroll
      for (int j = 0; j < 8; ++j) {
        int idx = tid + 256 * j;
        int row = idx >> 9, up = idx & 511;
        int byteoff = (row * 2048 + up * 4) ^ ((row & 3) << 5);
        *(unsigned*)(hb + byteoff) = (unsigned)recA[j];
      }
    }
    asm volatile("s_waitcnt lgkmcnt(0)" ::: "memory");
    __builtin_amdgcn_sched_barrier(0);
    __builtin_amdgcn_s_barrier();
    __builtin_amdgcn_sched_barrier(0);

    // speculative load of B's records (verified later; overlap with MFMA A)
    const unsigned long long* rbB = hrec + (((size_t)(gB * 2 + par)) << 11) + tid;
    unsigned long long recB[8];
#pragma unroll
    for (int j = 0; j < 8; ++j)
      recB[j] = __hip_atomic_load(rbB + 256 * j, __ATOMIC_RELAXED, __HIP_MEMORY_SCOPE_SYSTEM);

    // MFMA A
    {
      unsigned char* hb = hlds[par];
      f32x4 ac0 = {0.f, 0.f, 0.f, 0.f}, ac1 = ac0, ac2 = ac0, ac3 = ac0;
#pragma unroll
      for (int kt = 0; kt < 32; ++kt) {
        int ab = ((lane & 3) * 2048 + kt * 64 + lk * 16) ^ ((lane & 3) << 5);
        bf16x8 af = *(const bf16x8*)(hb + ab);
        if ((kt & 3) == 0)      ac0 = __builtin_amdgcn_mfma_f32_16x16x32_bf16(af, bfrag[kt], ac0, 0, 0, 0);
        else if ((kt & 3) == 1) ac1 = __builtin_amdgcn_mfma_f32_16x16x32_bf16(af, bfrag[kt], ac1, 0, 0, 0);
        else if ((kt & 3) == 2) ac2 = __builtin_amdgcn_mfma_f32_16x16x32_bf16(af, bfrag[kt], ac2, 0, 0, 0);
        else                    ac3 = __builtin_amdgcn_mfma_f32_16x16x32_bf16(af, bfrag[kt], ac3, 0, 0, 0);
      }
      f32x4 dsum = (ac0 + ac1) + (ac2 + ac3);

      float pre[4], oth[4];
#pragma unroll
      for (int rr = 0; rr < 4; ++rr) {
        pre[rr] = dsum[rr] + bf2f(pfA[rr]) * scl + bia;
        oth[rr] = __shfl_xor(pre[rr], 8);
      }
      if (lk == 0 && isH) {
        float hn[4];
#pragma unroll
        for (int rr = 0; rr < 4; ++rr) {
          float zz = 1.0f / (1.0f + __expf(-oth[rr]));
          float hc = fmaxf(pre[rr], 0.0f) * PKEEP;
          hn[rr] = zz * hownA[rr] + (1.0f - zz) * hc;
          hownA[rr] = hn[rr];
        }
        float pp[4];
#pragma unroll
        for (int rr = 0; rr < 4; ++rr) pp[rr] = __shfl_xor(hn[rr], 1);
        if ((lane & 1) == 0) {
          unsigned long long* hbn = hrec + (((size_t)(gA * 2 + npar)) << 11) + (unit >> 1);
#pragma unroll
          for (int rr = 0; rr < 4; ++rr) {
            unsigned long long rcd = ((unsigned long long)tagw << 32)
                                   | (unsigned)f2bf(hn[rr]) | ((unsigned)f2bf(pp[rr]) << 16);
            __hip_atomic_store(hbn + rr * 512, rcd,
                               __ATOMIC_RELAXED, __HIP_MEMORY_SCOPE_SYSTEM);
          }
#pragma unroll
          for (int rr = 0; rr < 4; ++rr) {
            float2 ov = {hn[rr], pp[rr]};
            *(float2*)(out + (size_t)(t * 32 + b0A + rr) * 1024 + unit) = ov;
          }
        }
      }
    }

    // ================= segment B: verify speculative read =================
    while (true) {
      unsigned bad = 0;
#pragma unroll
      for (int j = 0; j < 8; ++j)
        if ((unsigned)(recB[j] >> 32) < (unsigned)t) bad |= (1u << j);
      if (!bad) break;
      __builtin_amdgcn_s_sleep(1);
#pragma unroll
      for (int j = 0; j < 8; ++j)
        if (bad & (1u << j))
          recB[j] = __hip_atomic_load(rbB + 256 * j, __ATOMIC_RELAXED, __HIP_MEMORY_SCOPE_SYSTEM);
    }

    // unpack B -> hlds[2+par]
    {
      unsigned char* hb = hlds[2 + par];
#pragma unroll
      for (int j = 0; j < 8; ++j) {
        int idx = tid + 256 * j;
        int row = idx >> 9, up = idx & 511;
        int byteoff = (row * 2048 + up * 4) ^ ((row & 3) << 5);
        *(unsigned*)(hb + byteoff) = (unsigned)recB[j];
      }
    }
    asm volatile("s_waitcnt lgkmcnt(0)" ::: "memory");
    __builtin_amdgcn_sched_barrier(0);
    __builtin_amdgcn_s_barrier();
    __builtin_amdgcn_sched_barrier(0);

    // MFMA B
    {
      unsigned char* hb = hlds[2 + par];
      f32x4 ac0 = {0.f, 0.f, 0.f, 0.f}, ac1 = ac0, ac2 = ac0, ac3 = ac0;
#pragma unroll
      for (int kt = 0; kt < 32; ++kt) {
        int ab = ((lane & 3) * 2048 + kt * 64 + lk * 16) ^ ((lane & 3) << 5);
        bf16x8 af = *(const bf16x8*)(hb + ab);
        if ((kt & 3) == 0)      ac0 = __builtin_amdgcn_mfma_f32_16x16x32_bf16(af, bfrag[kt], ac0, 0, 0, 0);
        else if ((kt & 3) == 1) ac1 = __builtin_amdgcn_mfma_f32_16x16x32_bf16(af, bfrag[kt], ac1, 0, 0, 0);
        else if ((kt & 3) == 2) ac2 = __builtin_amdgcn_mfma_f32_16x16x32_bf16(af, bfrag[kt], ac2, 0, 0, 0);
        else                    ac3 = __builtin_amdgcn_mfma_f32_16x16x32_bf16(af, bfrag[kt], ac3, 0, 0, 0);
      }
      f32x4 dsum = (ac0 + ac1) + (ac2 + ac3);

      float pre[4], oth[4];
#pragma unroll
      for (int rr = 0; rr < 4; ++rr) {
        pre[rr] = dsum[rr] + bf2f(pfB[rr]) * scl + bia;
        oth[rr] = __shfl_xor(pre[rr], 8);
      }
      if (lk == 0 && isH) {
        float hn[4];
#pragma unroll
        for (int rr = 0; rr < 4; ++rr) {
          float zz = 1.0f / (1.0f + __expf(-oth[rr]));
          float hc = fmaxf(pre[rr], 0.0f) * PKEEP;
          hn[rr] = zz * hownB[rr] + (1.0f - zz) * hc;
          hownB[rr] = hn[rr];
        }
        float pp[4];
#pragma unroll
        for (int rr = 0; rr < 4; ++rr) pp[rr] = __shfl_xor(hn[rr], 1);
        if ((lane & 1) == 0) {
          unsigned long long* hbn = hrec + (((size_t)(gB * 2 + npar)) << 11) + (unit >> 1);
#pragma unroll
          for (int rr = 0; rr < 4; ++rr) {
            unsigned long long rcd = ((unsigned long long)tagw << 32)
                                   | (unsigned)f2bf(hn[rr]) | ((unsigned)f2bf(pp[rr]) << 16);
            __hip_atomic_store(hbn + rr * 512, rcd,
                               __ATOMIC_RELAXED, __HIP_MEMORY_SCOPE_SYSTEM);
          }
#pragma unroll
          for (int rr = 0; rr < 4; ++rr) {
            float2 ov = {hn[rr], pp[rr]};
            *(float2*)(out + (size_t)(t * 32 + b0B + rr) * 1024 + unit) = ov;
          }
        }
      }
    }

#pragma unroll
    for (int rr = 0; rr < 4; ++rr) {
      pfA[rr] = pn1A[rr]; pn1A[rr] = pn2A[rr];
      pfB[rr] = pn1B[rr]; pn1B[rr] = pn2B[rr];
    }
  }
}

// ---------------- launch ----------------
extern "C" void kernel_launch(void* const* d_in, const int* in_sizes, int n_in,
                              void* d_out, int out_size, void* d_ws, size_t ws_size,
                              hipStream_t stream) {
  (void)in_sizes; (void)n_in; (void)out_size; (void)ws_size;
  const float* x   = (const float*)d_in[0];
  const float* Wh  = (const float*)d_in[1];
  const float* Wz  = (const float*)d_in[2];
  const float* Uh  = (const float*)d_in[3];
  const float* Uz  = (const float*)d_in[4];
  const float* gwh = (const float*)d_in[5];
  const float* bwh = (const float*)d_in[6];
  const float* gwz = (const float*)d_in[7];
  const float* bwz = (const float*)d_in[8];

  char* ws = (char*)d_ws;
  float*              sums  = (float*)(ws + 0);                  // 8192 B
  float*              sumsq = (float*)(ws + 8192);               // 8192 B
  unsigned long long* hrec  = (unsigned long long*)(ws + 16384); // 262144 B
  unsigned int*       ctrl  = (unsigned int*)(ws + 278528);      // 128 B
  unsigned short*     Wb    = (unsigned short*)(ws + 278784);    // 2 MiB

  // zero stats + records + ctrl every call (graph-replay safe; tag=0 == valid h0=0)
  hipMemsetAsync(d_ws, 0, 278784, stream);
  k_convw<<<1024, 256, 0, stream>>>(Wh, Wz, Wb);
  // P (bf16) lives in d_out; scan overwrites it with f32 output in provably-ordered fashion
  k_gemm<<<8000, 256, 0, stream>>>(x, Wb, (unsigned short*)d_out, sums, sumsq);
  k_scan<<<NWG, 256, 0, stream>>>(Uh, Uz, gwh, bwh, gwz, bwz,
                                  (const unsigned short*)d_out, sums, sumsq,
                                  hrec, ctrl, (float*)d_out);
}